// Round 1
// baseline (1434.139 us; speedup 1.0000x reference)
//
#include <hip/hip_runtime.h>
#include <math.h>

// Problem constants
#define BB 4
#define CC 64
#define HH 128
#define WW 128
#define GG 8
#define COO 64
#define HWC (HH*WW)

// ---------------------------------------------------------------------------
// Transpose conv weights [Cout][Cin*9] -> [Cin*9][Cout] so per-(c,kk) weight
// rows are contiguous & wave-uniform in the conv kernel (scalar loads).
// ---------------------------------------------------------------------------
__global__ void transpose_w_kernel(const float* __restrict__ w, float* __restrict__ wT,
                                   int Cout, int Cin9, int n) {
    int i = blockIdx.x * 256 + threadIdx.x;
    if (i < n) {
        int co = i / Cin9;
        int ck = i - co * Cin9;
        wT[ck * Cout + co] = w[i];
    }
}

// ---------------------------------------------------------------------------
// Direct 3x3 conv, stride 1, pad 1, NCHW. Input may be a concat of two
// tensors (in0: C0 ch, in1: C1 ch). Each thread computes one pixel for RC
// consecutive output channels. act: 0=none, 1=leaky(0.1), 2=sigmoid,
// 3=sigmoid only on channels >= 144 (the om mask channels).
// ---------------------------------------------------------------------------
template<int RC>
__global__ __launch_bounds__(256) void conv3x3_kernel(
    const float* __restrict__ in0, int C0,
    const float* __restrict__ in1, int C1,
    const float* __restrict__ wT,
    const float* __restrict__ bias,
    float* __restrict__ out, int Cout, int act)
{
    const int tx = threadIdx.x & 15, ty = threadIdx.x >> 4;
    const int tilesX = WW / 16;
    const int tileX = blockIdx.x % tilesX, tileY = blockIdx.x / tilesX;
    const int b = blockIdx.y;
    const int co0 = blockIdx.z * RC;
    const int h = tileY * 16 + ty, w = tileX * 16 + tx;

    float acc[RC];
#pragma unroll
    for (int r = 0; r < RC; r++) acc[r] = 0.f;

    for (int s = 0; s < 2; s++) {
        const float* in = s ? in1 : in0;
        const int Cn = s ? C1 : C0;
        const int cbase = s ? C0 : 0;
        if (in == nullptr) continue;
        for (int c = 0; c < Cn; c++) {
            const float* ip = in + ((size_t)(b * Cn + c)) * HWC;
#pragma unroll
            for (int kk = 0; kk < 9; kk++) {
                const int hy = h + kk / 3 - 1;
                const int wx = w + (kk % 3) - 1;
                float v = 0.f;
                if (hy >= 0 && hy < HH && wx >= 0 && wx < WW) v = ip[hy * WW + wx];
                const float* wp = wT + ((size_t)((cbase + c) * 9 + kk)) * Cout + co0;
#pragma unroll
                for (int r = 0; r < RC; r++) acc[r] = fmaf(v, wp[r], acc[r]);
            }
        }
    }

#pragma unroll
    for (int r = 0; r < RC; r++) {
        float o = acc[r] + bias[co0 + r];
        if (act == 1)      o = (o >= 0.f) ? o : 0.1f * o;
        else if (act == 2) o = 1.f / (1.f + __expf(-o));
        else if (act == 3 && (co0 + r) >= 144) o = 1.f / (1.f + __expf(-o));
        out[((size_t)(b * Cout + co0 + r)) * HWC + h * WW + w] = o;
    }
}

// ---------------------------------------------------------------------------
// Fused dual modulated deformable conv (DCNv2), stride 1, pad 1.
// Both deform convs share offsets (om channels 0..143). Mask for x is
// sigmoid-ed om channels 144..215 (applied already in conv epilogue); mask
// for share is em (72 ch). One thread per (b,g,h,w): computes all 8 output
// channels of its group for BOTH outputs. Wave = 64 consecutive w -> (b,g,h)
// wave-uniform, so w_dc reads are scalar.
// ---------------------------------------------------------------------------
__global__ __launch_bounds__(256) void deform_fused_kernel(
    const float* __restrict__ x, const float* __restrict__ share,
    const float* __restrict__ om, const float* __restrict__ em,
    const float* __restrict__ wdc, const float* __restrict__ bdc,
    float* __restrict__ outx, float* __restrict__ outs)
{
    const int tid = blockIdx.x * 256 + threadIdx.x;
    const int w = tid & (WW - 1);
    const int h = (tid >> 7) & (HH - 1);
    const int g = (tid >> 14) & (GG - 1);
    const int b = tid >> 17;

    const int pix = h * WW + w;
    const float* omb = om + (size_t)b * 216 * HWC + pix;
    const float* emb = em + (size_t)b * 72 * HWC + pix;
    const float* xb = x + ((size_t)(b * CC + g * 8)) * HWC;
    const float* sb = share + ((size_t)(b * CC + g * 8)) * HWC;

    float accx[8], accs[8];
#pragma unroll
    for (int o = 0; o < 8; o++) { accx[o] = 0.f; accs[o] = 0.f; }

    for (int kk = 0; kk < 9; kk++) {
        const float dy = omb[(size_t)(g * 18 + kk * 2) * HWC];
        const float dx = omb[(size_t)(g * 18 + kk * 2 + 1) * HWC];
        const float m1 = omb[(size_t)(144 + g * 9 + kk) * HWC]; // already sigmoid
        const float m2 = emb[(size_t)(g * 9 + kk) * HWC];

        const float py = (float)(h - 1 + kk / 3) + dy;
        const float px = (float)(w - 1 + kk % 3) + dx;
        const float y0f = floorf(py), x0f = floorf(px);
        const float ly = py - y0f, lx = px - x0f;
        const int y0 = (int)y0f, x0 = (int)x0f;
        const int y1 = y0 + 1, x1 = x0 + 1;
        const bool vy0 = (y0 >= 0) && (y0 < HH), vy1 = (y1 >= 0) && (y1 < HH);
        const bool vx0 = (x0 >= 0) && (x0 < WW), vx1 = (x1 >= 0) && (x1 < WW);
        float w00 = (1.f - ly) * (1.f - lx); if (!(vy0 && vx0)) w00 = 0.f;
        float w01 = (1.f - ly) * lx;         if (!(vy0 && vx1)) w01 = 0.f;
        float w10 = ly * (1.f - lx);         if (!(vy1 && vx0)) w10 = 0.f;
        float w11 = ly * lx;                 if (!(vy1 && vx1)) w11 = 0.f;
        const int cy0 = min(max(y0, 0), HH - 1), cy1 = min(max(y1, 0), HH - 1);
        const int cx0 = min(max(x0, 0), WW - 1), cx1 = min(max(x1, 0), WW - 1);
        const int i00 = cy0 * WW + cx0, i01 = cy0 * WW + cx1;
        const int i10 = cy1 * WW + cx0, i11 = cy1 * WW + cx1;

#pragma unroll
        for (int c = 0; c < 8; c++) {
            const float* xc = xb + (size_t)c * HWC;
            const float* sc = sb + (size_t)c * HWC;
            float vx = w00 * xc[i00] + w01 * xc[i01] + w10 * xc[i10] + w11 * xc[i11];
            float vs = w00 * sc[i00] + w01 * sc[i01] + w10 * sc[i10] + w11 * sc[i11];
            vx *= m1;
            vs *= m2;
#pragma unroll
            for (int o = 0; o < 8; o++) {
                const float wv = wdc[((size_t)((g * 8 + o) * 8 + c)) * 9 + kk];
                accx[o] = fmaf(vx, wv, accx[o]);
                accs[o] = fmaf(vs, wv, accs[o]);
            }
        }
    }

#pragma unroll
    for (int o = 0; o < 8; o++) {
        const float bv = bdc[g * 8 + o];
        outx[((size_t)(b * COO + g * 8 + o)) * HWC + pix] = accx[o] + bv;
        outs[((size_t)(b * COO + g * 8 + o)) * HWC + pix] = accs[o] + bv;
    }
}

// ---------------------------------------------------------------------------
extern "C" void kernel_launch(void* const* d_in, const int* in_sizes, int n_in,
                              void* d_out, int out_size, void* d_ws, size_t ws_size,
                              hipStream_t stream) {
    const float* x      = (const float*)d_in[0];
    const float* share  = (const float*)d_in[1];
    const float* offf   = (const float*)d_in[2];
    const float* w_om   = (const float*)d_in[3];
    const float* b_om   = (const float*)d_in[4];
    const float* w_em1  = (const float*)d_in[5];
    const float* b_em1  = (const float*)d_in[6];
    const float* w_em2  = (const float*)d_in[7];
    const float* b_em2  = (const float*)d_in[8];
    const float* w_dc   = (const float*)d_in[9];
    const float* b_dc   = (const float*)d_in[10];

    // Workspace layout (floats):
    float* ws      = (float*)d_ws;
    float* wT_om   = ws;                       // 576*216  = 124416
    float* wT_em1  = wT_om  + 124416;          // 1152*64  = 73728
    float* wT_em2  = wT_em1 + 73728;           // 576*72   = 41472
    float* om      = wT_em2 + 41472;           // 4*216*16384 = 14155776
    float* em_mid  = om     + 14155776;        // 4*64*16384  = 4194304
    float* em      = em_mid + 4194304;         // 4*72*16384  = 4718592

    float* outx = (float*)d_out;               // 4*64*16384 = 4194304
    float* outs = outx + 4194304;

    dim3 blk(256);

    transpose_w_kernel<<<(124416 + 255) / 256, blk, 0, stream>>>(w_om,  wT_om,  216, 576,  124416);
    transpose_w_kernel<<<(73728  + 255) / 256, blk, 0, stream>>>(w_em1, wT_em1, 64,  1152, 73728);
    transpose_w_kernel<<<(41472  + 255) / 256, blk, 0, stream>>>(w_em2, wT_em2, 72,  576,  41472);

    // om = conv3x3(offset_feat) 64->216, sigmoid on mask channels (>=144)
    conv3x3_kernel<24><<<dim3(64, 4, 9), blk, 0, stream>>>(offf, 64, nullptr, 0, wT_om, b_om, om, 216, 3);
    // em_mid = leaky_relu(conv3x3(concat(share, offset_feat))) 128->64
    conv3x3_kernel<16><<<dim3(64, 4, 4), blk, 0, stream>>>(share, 64, offf, 64, wT_em1, b_em1, em_mid, 64, 1);
    // em = sigmoid(conv3x3(em_mid)) 64->72
    conv3x3_kernel<24><<<dim3(64, 4, 3), blk, 0, stream>>>(em_mid, 64, nullptr, 0, wT_em2, b_em2, em, 72, 2);

    // fused dual deformable conv
    deform_fused_kernel<<<dim3(BB * GG * HH * WW / 256), blk, 0, stream>>>(
        x, share, om, em, w_dc, b_dc, outx, outs);
}

// Round 2
// 478.588 us; speedup vs baseline: 2.9966x; 2.9966x over previous
//
#include <hip/hip_runtime.h>
#include <math.h>

// Problem constants
#define BB 4
#define CC 64
#define HH 128
#define WW 128
#define GG 8
#define COO 64
#define HWC (HH*WW)

typedef float f32x16 __attribute__((ext_vector_type(16)));
typedef __bf16 bf16x8 __attribute__((ext_vector_type(8)));

__device__ __forceinline__ unsigned short bf16_rn(float f) {
    unsigned int u = __float_as_uint(f);
    unsigned int r = (u + 0x7fffu + ((u >> 16) & 1u)) >> 16;
    return (unsigned short)r;
}
__device__ __forceinline__ float b2f(unsigned short u) {
    return __uint_as_float(((unsigned int)u) << 16);
}

// ---------------------------------------------------------------------------
// NCHW fp32 -> NHWC bf16 (C=64), LDS-tiled for coalescing both sides.
// ---------------------------------------------------------------------------
__global__ __launch_bounds__(256) void to_nhwc_kernel(const float* __restrict__ in,
                                                      unsigned short* __restrict__ out) {
    __shared__ unsigned short lds[64][66];
    const int b = blockIdx.y;
    const int pix0 = blockIdx.x * 64;
    const int t = threadIdx.x;
    {
        const int p = t & 63, q = t >> 6;
#pragma unroll
        for (int i = 0; i < 16; i++) {
            int c = i * 4 + q;
            lds[c][p] = bf16_rn(in[((size_t)b * 64 + c) * HWC + pix0 + p]);
        }
    }
    __syncthreads();
    {
        const int c = t & 63, pb = t >> 6;
#pragma unroll
        for (int i = 0; i < 16; i++) {
            int pl = i * 4 + pb;
            out[((size_t)b * HWC + pix0 + pl) * 64 + c] = lds[c][pl];
        }
    }
}

// ---------------------------------------------------------------------------
// Pack conv weights [Cout][CinTot][3][3] fp32 into MFMA A-fragment order:
// wp[((seg*9+kk)*4+cg)][co_pad][16c] bf16, zero-padded for co >= Cout.
// ---------------------------------------------------------------------------
__global__ void pack_w_kernel(const float* __restrict__ w, unsigned short* __restrict__ wp,
                              int Cout, int COP, int CinTot, int n) {
    int idx = blockIdx.x * 256 + threadIdx.x;
    if (idx >= n) return;
    int i  = idx & 15;
    int co = (idx >> 4) % COP;
    int t  = idx / (16 * COP);       // t = (seg*9+kk)*4+cg
    int cg = t & 3;
    int kk = (t >> 2) % 9;
    int seg = t / 36;
    int cin = seg * 64 + cg * 16 + i;
    float v = (co < Cout) ? w[((size_t)co * CinTot + cin) * 9 + kk] : 0.f;
    wp[idx] = bf16_rn(v);
}

// ---------------------------------------------------------------------------
// Implicit-GEMM 3x3 conv via mfma_f32_32x32x16_bf16.
// Wave tile: 32 Cout x 128 pix (one image row). Block = 4 waves = 4 rows.
// grid = (B*H/4, COP/32). Inputs are NHWC bf16 segments of 64 channels.
// A frag: a[j] = W[co=co0+lane&31][k = kk*16 + (lane>>5)*8+j]  (packed wp)
// B frag: b[j] = in[b][rr][cc][c = cg*16 + (lane>>5)*8+j]
// D: col(pix)=lane&31, row(co)=(reg&3)+8*(reg>>2)+4*(lane>>5)
// out_mode: 0 = NCHW fp32, 1 = NHWC bf16, 2 = NCHW bf16
// act: 0 none, 1 leaky(0.1), 2 sigmoid, 3 sigmoid for co>=144
// ---------------------------------------------------------------------------
template<int NSEG>
__global__ __launch_bounds__(256, 4) void conv_mfma_kernel(
    const unsigned short* __restrict__ in0,
    const unsigned short* __restrict__ in1,
    const unsigned short* __restrict__ wp,
    const float* __restrict__ bias,
    void* __restrict__ out,
    int Cout, int COP, int out_mode, int act)
{
    const int lane = threadIdx.x & 63;
    const int wid  = threadIdx.x >> 6;
    const int l31  = lane & 31;
    const int half = lane >> 5;
    const int b    = blockIdx.x >> 5;
    const int r    = ((blockIdx.x & 31) << 2) + wid;   // image row, wave-uniform
    const int co0  = blockIdx.y * 32;

    f32x16 acc[4];
#pragma unroll
    for (int nt = 0; nt < 4; nt++)
#pragma unroll
        for (int rg = 0; rg < 16; rg++) acc[nt][rg] = 0.f;

    bf16x8 bz;
#pragma unroll
    for (int i = 0; i < 8; i++) bz[i] = (__bf16)0.f;

#pragma unroll
    for (int seg = 0; seg < NSEG; seg++) {
        const unsigned short* in = seg ? in1 : in0;
        const unsigned short* inb = in + (size_t)b * HWC * 64;
        for (int kk = 0; kk < 9; kk++) {
            const int rr = r + kk / 3 - 1;
            if ((unsigned)rr < (unsigned)HH) {
                const int dxo = kk % 3 - 1;
                const size_t rowbase = (size_t)rr * WW * 64;
#pragma unroll
                for (int cg = 0; cg < 4; cg++) {
                    bf16x8 afrag = *(const bf16x8*)(wp +
                        ((size_t)(((seg * 9 + kk) * 4 + cg) * COP + co0 + l31) * 16 + half * 8));
#pragma unroll
                    for (int nt = 0; nt < 4; nt++) {
                        const int cc = nt * 32 + l31 + dxo;
                        bf16x8 bfrag = bz;
                        if ((unsigned)cc < (unsigned)WW)
                            bfrag = *(const bf16x8*)(inb + rowbase + (size_t)cc * 64 + cg * 16 + half * 8);
                        acc[nt] = __builtin_amdgcn_mfma_f32_32x32x16_bf16(afrag, bfrag, acc[nt], 0, 0, 0);
                    }
                }
            }
        }
    }

    // Epilogue
#pragma unroll
    for (int nt = 0; nt < 4; nt++) {
#pragma unroll
        for (int rg = 0; rg < 16; rg++) {
            const int row = (rg & 3) + 8 * (rg >> 2) + 4 * half;
            const int co = co0 + row;
            if (co < Cout) {
                float v = acc[nt][rg] + bias[co];
                if (act == 1)      v = (v >= 0.f) ? v : 0.1f * v;
                else if (act == 2) v = 1.f / (1.f + __expf(-v));
                else if (act == 3 && co >= 144) v = 1.f / (1.f + __expf(-v));
                const int pix = r * WW + nt * 32 + l31;
                if (out_mode == 0)
                    ((float*)out)[((size_t)b * Cout + co) * HWC + pix] = v;
                else if (out_mode == 1)
                    ((unsigned short*)out)[((size_t)b * HWC + pix) * Cout + co] = bf16_rn(v);
                else
                    ((unsigned short*)out)[((size_t)b * Cout + co) * HWC + pix] = bf16_rn(v);
            }
        }
    }
}

// ---------------------------------------------------------------------------
// Fused dual modulated deformable conv. x/share in NHWC bf16 (8ch/group
// contiguous -> one dwordx4 gather per corner). om NCHW bf16, em NCHW fp32.
// One thread per (b,g,h,w), 8 output channels for both outputs.
// ---------------------------------------------------------------------------
__device__ __forceinline__ void bilerp8(const unsigned short* __restrict__ base,
                                        int i00, int i01, int i10, int i11,
                                        float w00, float w01, float w10, float w11,
                                        float* v) {
    uint4 q00 = *(const uint4*)(base + (size_t)i00 * 64);
    uint4 q01 = *(const uint4*)(base + (size_t)i01 * 64);
    uint4 q10 = *(const uint4*)(base + (size_t)i10 * 64);
    uint4 q11 = *(const uint4*)(base + (size_t)i11 * 64);
    const unsigned int* a = (const unsigned int*)&q00;
    const unsigned int* b = (const unsigned int*)&q01;
    const unsigned int* c = (const unsigned int*)&q10;
    const unsigned int* d = (const unsigned int*)&q11;
#pragma unroll
    for (int i = 0; i < 4; i++) {
        float a0 = __uint_as_float(a[i] << 16), a1 = __uint_as_float(a[i] & 0xffff0000u);
        float b0 = __uint_as_float(b[i] << 16), b1 = __uint_as_float(b[i] & 0xffff0000u);
        float c0 = __uint_as_float(c[i] << 16), c1 = __uint_as_float(c[i] & 0xffff0000u);
        float d0 = __uint_as_float(d[i] << 16), d1 = __uint_as_float(d[i] & 0xffff0000u);
        v[2 * i]     = w00 * a0 + w01 * b0 + w10 * c0 + w11 * d0;
        v[2 * i + 1] = w00 * a1 + w01 * b1 + w10 * c1 + w11 * d1;
    }
}

__global__ __launch_bounds__(256, 4) void deform_fused_kernel(
    const unsigned short* __restrict__ xh, const unsigned short* __restrict__ shh,
    const unsigned short* __restrict__ om, const float* __restrict__ em,
    const float* __restrict__ wdc, const float* __restrict__ bdc,
    float* __restrict__ outx, float* __restrict__ outs)
{
    const int tid = blockIdx.x * 256 + threadIdx.x;
    const int w = tid & (WW - 1);
    const int h = (tid >> 7) & (HH - 1);
    const int g = (tid >> 14) & (GG - 1);
    const int b = tid >> 17;

    const int pix = h * WW + w;
    const unsigned short* omb = om + (size_t)b * 216 * HWC + pix;
    const float* emb = em + (size_t)b * 72 * HWC + pix;
    const unsigned short* xb = xh + (size_t)b * HWC * 64 + g * 8;
    const unsigned short* sb = shh + (size_t)b * HWC * 64 + g * 8;

    float accx[8], accs[8];
#pragma unroll
    for (int o = 0; o < 8; o++) { accx[o] = 0.f; accs[o] = 0.f; }

    for (int kk = 0; kk < 9; kk++) {
        const float dy = b2f(omb[(size_t)(g * 18 + kk * 2) * HWC]);
        const float dx = b2f(omb[(size_t)(g * 18 + kk * 2 + 1) * HWC]);
        const float m1 = b2f(omb[(size_t)(144 + g * 9 + kk) * HWC]); // sigmoided
        const float m2 = emb[(size_t)(g * 9 + kk) * HWC];

        const float py = (float)(h - 1 + kk / 3) + dy;
        const float px = (float)(w - 1 + kk % 3) + dx;
        const float y0f = floorf(py), x0f = floorf(px);
        const float ly = py - y0f, lx = px - x0f;
        const int y0 = (int)y0f, x0 = (int)x0f;
        const int y1 = y0 + 1, x1 = x0 + 1;
        const bool vy0 = (y0 >= 0) && (y0 < HH), vy1 = (y1 >= 0) && (y1 < HH);
        const bool vx0 = (x0 >= 0) && (x0 < WW), vx1 = (x1 >= 0) && (x1 < WW);
        float w00 = (1.f - ly) * (1.f - lx); if (!(vy0 && vx0)) w00 = 0.f;
        float w01 = (1.f - ly) * lx;         if (!(vy0 && vx1)) w01 = 0.f;
        float w10 = ly * (1.f - lx);         if (!(vy1 && vx0)) w10 = 0.f;
        float w11 = ly * lx;                 if (!(vy1 && vx1)) w11 = 0.f;
        const int cy0 = min(max(y0, 0), HH - 1), cy1 = min(max(y1, 0), HH - 1);
        const int cx0 = min(max(x0, 0), WW - 1), cx1 = min(max(x1, 0), WW - 1);
        const int i00 = cy0 * WW + cx0, i01 = cy0 * WW + cx1;
        const int i10 = cy1 * WW + cx0, i11 = cy1 * WW + cx1;

        float vx[8], vs[8];
        bilerp8(xb, i00, i01, i10, i11, w00, w01, w10, w11, vx);
        bilerp8(sb, i00, i01, i10, i11, w00, w01, w10, w11, vs);

#pragma unroll
        for (int c = 0; c < 8; c++) { vx[c] *= m1; vs[c] *= m2; }

#pragma unroll
        for (int c = 0; c < 8; c++) {
#pragma unroll
            for (int o = 0; o < 8; o++) {
                const float wv = wdc[((size_t)((g * 8 + o) * 8 + c)) * 9 + kk];
                accx[o] = fmaf(vx[c], wv, accx[o]);
                accs[o] = fmaf(vs[c], wv, accs[o]);
            }
        }
    }

#pragma unroll
    for (int o = 0; o < 8; o++) {
        const float bv = bdc[g * 8 + o];
        outx[((size_t)(b * COO + g * 8 + o)) * HWC + pix] = accx[o] + bv;
        outs[((size_t)(b * COO + g * 8 + o)) * HWC + pix] = accs[o] + bv;
    }
}

// ---------------------------------------------------------------------------
extern "C" void kernel_launch(void* const* d_in, const int* in_sizes, int n_in,
                              void* d_out, int out_size, void* d_ws, size_t ws_size,
                              hipStream_t stream) {
    const float* x      = (const float*)d_in[0];
    const float* share  = (const float*)d_in[1];
    const float* offf   = (const float*)d_in[2];
    const float* w_om   = (const float*)d_in[3];
    const float* b_om   = (const float*)d_in[4];
    const float* w_em1  = (const float*)d_in[5];
    const float* b_em1  = (const float*)d_in[6];
    const float* w_em2  = (const float*)d_in[7];
    const float* b_em2  = (const float*)d_in[8];
    const float* w_dc   = (const float*)d_in[9];
    const float* b_dc   = (const float*)d_in[10];

    // Workspace layout
    float* em = (float*)d_ws;                         // 4*72*16384 f32 = 18.87MB
    unsigned short* us = (unsigned short*)(em + 4718592);
    unsigned short* xh     = us;                      // 4194304 ush
    unsigned short* shh    = xh  + 4194304;           // 4194304
    unsigned short* ofh    = shh + 4194304;           // 4194304
    unsigned short* emh    = ofh + 4194304;           // 4194304 (em_mid NHWC bf16)
    unsigned short* om_b   = emh + 4194304;           // 4*216*16384 = 14155776 (NCHW bf16)
    unsigned short* wp_om  = om_b + 14155776;         // 36*224*16 = 129024
    unsigned short* wp_em1 = wp_om + 129024;          // 72*64*16  = 73728
    unsigned short* wp_em2 = wp_em1 + 73728;          // 36*96*16  = 55296

    float* outx = (float*)d_out;
    float* outs = outx + 4194304;

    dim3 blk(256);

    // Repack inputs to NHWC bf16
    to_nhwc_kernel<<<dim3(HWC / 64, BB), blk, 0, stream>>>(x, xh);
    to_nhwc_kernel<<<dim3(HWC / 64, BB), blk, 0, stream>>>(share, shh);
    to_nhwc_kernel<<<dim3(HWC / 64, BB), blk, 0, stream>>>(offf, ofh);

    // Pack weights
    pack_w_kernel<<<(129024 + 255) / 256, blk, 0, stream>>>(w_om,  wp_om,  216, 224, 64,  129024);
    pack_w_kernel<<<(73728  + 255) / 256, blk, 0, stream>>>(w_em1, wp_em1, 64,  64,  128, 73728);
    pack_w_kernel<<<(55296  + 255) / 256, blk, 0, stream>>>(w_em2, wp_em2, 72,  96,  64,  55296);

    // om = conv(offset_feat) 64->216, sigmoid on mask channels, NCHW bf16
    conv_mfma_kernel<1><<<dim3(BB * HH / 4, 7), blk, 0, stream>>>(
        ofh, nullptr, wp_om, b_om, om_b, 216, 224, 2, 3);
    // em_mid = leaky(conv(concat(share, offf))) 128->64, NHWC bf16
    conv_mfma_kernel<2><<<dim3(BB * HH / 4, 2), blk, 0, stream>>>(
        shh, ofh, wp_em1, b_em1, emh, 64, 64, 1, 1);
    // em = sigmoid(conv(em_mid)) 64->72, NCHW fp32
    conv_mfma_kernel<1><<<dim3(BB * HH / 4, 3), blk, 0, stream>>>(
        emh, nullptr, wp_em2, b_em2, em, 72, 96, 0, 2);

    // fused dual deformable conv
    deform_fused_kernel<<<dim3(BB * GG * HH * WW / 256), blk, 0, stream>>>(
        xh, shh, om_b, em, w_dc, b_dc, outx, outs);
}